// Round 1
// baseline (1650.444 us; speedup 1.0000x reference)
//
#include <hip/hip_runtime.h>
#include <hip/hip_bf16.h>
#include <cstdint>

#define NN   100000
#define TT   4
#define EE   250000
#define LL   2
#define NCH  49            // ceil(NN/2048)
#define EPN  (EE + NN)     // 350000

static __device__ __forceinline__ float gelu_exact(float v) {
    return 0.5f * v * (1.0f + erff(v * 0.7071067811865476f));
}
static __device__ __forceinline__ float wave_sum64(float v) {
    #pragma unroll
    for (int m = 32; m; m >>= 1) v += __shfl_xor(v, m, 64);
    return v;
}

// ---------------------------------------------------------------------------
// Prep: collapsed logit weights w_coll[l][d][col] (col = t*8 + side*4 + h),
// permuted/scaled projection Bproj[l][t][h*64+d][c] = 0.25*W_src[l,t,d,h*64+c],
// bias_sum[l][c] = sum_t conv_bias[l,t,c].
// ---------------------------------------------------------------------------
__global__ __launch_bounds__(256) void k_prep(
    const float* __restrict__ Wsrc, const float* __restrict__ Wdst,
    const float* __restrict__ asrc, const float* __restrict__ adst,
    const float* __restrict__ cb,
    float* __restrict__ wcoll, float* __restrict__ bproj, float* __restrict__ bsum)
{
    int id = blockIdx.x * 256 + threadIdx.x;   // grid = 131072 exactly
    {   // Bproj
        int c  = id & 63;
        int hd = (id >> 6) & 255;
        int t  = (id >> 14) & 3;
        int l  = (id >> 16) & 1;
        int h = hd >> 6, d = hd & 63;
        bproj[id] = 0.25f * Wsrc[(((l * 4 + t) * 64 + d) * 256) + h * 64 + c];
    }
    if (id < LL * 64 * 64) {   // w_coll
        int col = id & 63;
        int d   = (id >> 6) & 63;
        int l   = id >> 12;
        int t = col >> 3, side = (col >> 2) & 1, h = col & 3;
        const float* W = side ? Wdst : Wsrc;
        const float* a = side ? adst : asrc;
        int wb = ((l * 4 + t) * 64 + d) * 256 + h * 64;
        int ab = ((l * 4 + t) * 4 + h) * 64;
        float s = 0.f;
        #pragma unroll 8
        for (int c2 = 0; c2 < 64; ++c2) s = fmaf(W[wb + c2], a[ab + c2], s);
        wcoll[id] = s;
    }
    if (id < LL * 64) {        // bias_sum
        int l = id >> 6, c = id & 63;
        float s = 0.f;
        for (int t = 0; t < TT; ++t) s += cb[(l * 4 + t) * 64 + c];
        bsum[id] = s;
    }
}

// ---------------------------------------------------------------------------
// CSR build
// ---------------------------------------------------------------------------
__global__ void k_hist(const int* __restrict__ ei, int* __restrict__ cursor) {
    int id = blockIdx.x * 256 + threadIdx.x;
    if (id >= TT * EE) return;
    int t = id / EE, e = id - t * EE;
    int d = ei[(t * 2 + 1) * EE + e];
    atomicAdd(&cursor[t * NN + d], 1);
}

__global__ __launch_bounds__(256) void k_scan1(const int* __restrict__ deg,
                                               int* __restrict__ csum) {
    int b = blockIdx.x, t = b / NCH, cc = b - t * NCH;
    int tid = threadIdx.x;
    int base = cc * 2048 + tid * 8;
    int s = 0;
    #pragma unroll
    for (int i = 0; i < 8; ++i) {
        int idx = base + i;
        if (idx < NN) s += deg[t * NN + idx] + 1;   // +1: self loop
    }
    #pragma unroll
    for (int m = 32; m; m >>= 1) s += __shfl_xor(s, m, 64);
    __shared__ int ws4[4];
    int lane = tid & 63, wid = tid >> 6;
    if (lane == 0) ws4[wid] = s;
    __syncthreads();
    if (tid == 0) csum[b] = ws4[0] + ws4[1] + ws4[2] + ws4[3];
}

__global__ void k_scan2(const int* __restrict__ csum, int* __restrict__ cbase,
                        int* __restrict__ row_ptr) {
    int t = threadIdx.x;
    if (t >= TT) return;
    int base = 0;
    for (int c = 0; c < NCH; ++c) {
        cbase[t * NCH + c] = base;
        base += csum[t * NCH + c];
    }
    row_ptr[t * (NN + 1) + NN] = base;   // = EE + NN
}

__global__ __launch_bounds__(256) void k_scan3(int* __restrict__ cursor,
                                               const int* __restrict__ cbase,
                                               int* __restrict__ row_ptr) {
    int b = blockIdx.x, t = b / NCH, cc = b - t * NCH;
    int tid = threadIdx.x, lane = tid & 63, wid = tid >> 6;
    int base = cc * 2048 + tid * 8;
    int vals[8], ts = 0;
    #pragma unroll
    for (int i = 0; i < 8; ++i) {
        int idx = base + i;
        int v = (idx < NN) ? cursor[t * NN + idx] + 1 : 0;
        vals[i] = v; ts += v;
    }
    int v = ts;
    #pragma unroll
    for (int off = 1; off < 64; off <<= 1) {
        int u = __shfl_up(v, off, 64);
        if (lane >= off) v += u;
    }
    __shared__ int wt[4];
    if (lane == 63) wt[wid] = v;
    __syncthreads();
    int wbase = 0;
    for (int w = 0; w < wid; ++w) wbase += wt[w];
    int run = cbase[t * NCH + cc] + wbase + (v - ts);
    #pragma unroll
    for (int i = 0; i < 8; ++i) {
        int idx = base + i;
        if (idx < NN) {
            row_ptr[t * (NN + 1) + idx] = run;
            cursor[t * NN + idx] = run;     // becomes scatter write-head
        }
        run += vals[i];
    }
}

__global__ void k_scatter(const int* __restrict__ ei, int* __restrict__ cursor,
                          int* __restrict__ col) {
    int id = blockIdx.x * 256 + threadIdx.x;
    if (id >= TT * EPN) return;
    int t = id / EPN, r = id - t * EPN;
    int s, d;
    if (r < EE) { s = ei[t * 2 * EE + r]; d = ei[(t * 2 + 1) * EE + r]; }
    else        { s = d = r - EE; }
    int pos = atomicAdd(&cursor[t * NN + d], 1);
    col[(size_t)t * EPN + pos] = s;
}

// ---------------------------------------------------------------------------
// Tiled GEMM: C[N,64] (+)= A[N,K] @ B[K,64].  128-row tile, K-chunks of 64 in
// LDS, 8x4 register tile per thread (32 FMA per 3 ds_read_b128 -> VALU-bound).
// ---------------------------------------------------------------------------
template <int K, bool ACCUM>
__global__ __launch_bounds__(256) void k_gemm64(const float* __restrict__ A,
                                                const float* __restrict__ B,
                                                float* __restrict__ C, int nrows)
{
    constexpr int KC = 64, RT = 128, LDA = RT + 4;   // LDA=132: 16B-aligned rows, bank-safe
    __shared__ float sB[KC * 64];       // 16 KB
    __shared__ float sA[KC * LDA];      // 33.8 KB
    const int tid = threadIdx.x;
    const int rowbase = blockIdx.x * RT;
    const int jc = tid & 15;            // cols 4*jc..4*jc+3
    const int rg = tid >> 4;            // rows rg*8..rg*8+7
    const int lr = tid & 127;           // staging row
    const int kh = tid >> 7;            // staging K-half

    float acc[8][4];
    #pragma unroll
    for (int i = 0; i < 8; ++i)
        #pragma unroll
        for (int j = 0; j < 4; ++j) acc[i][j] = 0.f;

    for (int kc = 0; kc < K; kc += KC) {
        __syncthreads();
        // stage B chunk (coalesced float4)
        const float4* Bg = (const float4*)(B + kc * 64);
        float4* sB4 = (float4*)sB;
        #pragma unroll
        for (int j = 0; j < 4; ++j) sB4[tid + j * 256] = Bg[tid + j * 256];
        // stage A chunk transposed
        int row = rowbase + lr;
        const float* Ap = A + (size_t)row * K + kc + kh * 32;
        #pragma unroll
        for (int j = 0; j < 8; ++j) {
            float4 v = (row < nrows) ? *(const float4*)(Ap + j * 4)
                                     : make_float4(0.f, 0.f, 0.f, 0.f);
            int k = kh * 32 + j * 4;
            sA[(k + 0) * LDA + lr] = v.x;
            sA[(k + 1) * LDA + lr] = v.y;
            sA[(k + 2) * LDA + lr] = v.z;
            sA[(k + 3) * LDA + lr] = v.w;
        }
        __syncthreads();
        #pragma unroll
        for (int k = 0; k < KC; ++k) {
            float4 b4 = *(const float4*)&sB[k * 64 + jc * 4];
            float4 a0 = *(const float4*)&sA[k * LDA + rg * 8];
            float4 a1 = *(const float4*)&sA[k * LDA + rg * 8 + 4];
            float av[8] = {a0.x, a0.y, a0.z, a0.w, a1.x, a1.y, a1.z, a1.w};
            float bv[4] = {b4.x, b4.y, b4.z, b4.w};
            #pragma unroll
            for (int i = 0; i < 8; ++i)
                #pragma unroll
                for (int j = 0; j < 4; ++j)
                    acc[i][j] = fmaf(av[i], bv[j], acc[i][j]);
        }
    }
    #pragma unroll
    for (int i = 0; i < 8; ++i) {
        int row = rowbase + rg * 8 + i;
        if (row < nrows) {
            float* Cp = C + (size_t)row * 64 + jc * 4;
            float4 r;
            r.x = acc[i][0]; r.y = acc[i][1]; r.z = acc[i][2]; r.w = acc[i][3];
            if (ACCUM) {
                float4 c0 = *(const float4*)Cp;
                r.x += c0.x; r.y += c0.y; r.z += c0.z; r.w += c0.w;
            }
            *(float4*)Cp = r;
        }
    }
}

// ---------------------------------------------------------------------------
// Feature epilogue: x = gelu(LN(y + lin_b)) + l2norm(emb).  One wave per row.
// ---------------------------------------------------------------------------
__global__ __launch_bounds__(256) void k_feat_post(
    const float* __restrict__ y, const float* __restrict__ lin_b,
    const float* __restrict__ ln_g, const float* __restrict__ ln_b,
    const float* __restrict__ emb, float* __restrict__ xout)
{
    int n = (blockIdx.x << 2) + (threadIdx.x >> 6);
    int c = threadIdx.x & 63;
    size_t base = (size_t)n * 64 + c;
    float v = y[base] + lin_b[c];
    float mean = wave_sum64(v) * 0.015625f;
    float t = v - mean;
    float var = wave_sum64(t * t) * 0.015625f;
    float vn = t * (1.0f / sqrtf(var + 1e-5f)) * ln_g[c] + ln_b[c];
    float g = gelu_exact(vn);
    float e = emb[base];
    float nrm = sqrtf(wave_sum64(e * e));
    xout[base] = g + e / fmaxf(nrm, 1e-12f);
}

// ---------------------------------------------------------------------------
// Edge aggregation: one wave per destination node.  Single pass over incoming
// edges; z[n][h*64+d] = (sum_e p_e,h * x[src_e,d]) / S[n,h].  No atomics.
// ---------------------------------------------------------------------------
__global__ __launch_bounds__(256) void k_edge(
    const float* __restrict__ x, const float* __restrict__ s_all,
    const int* __restrict__ row_ptr, const int* __restrict__ col,
    float* __restrict__ z, int toff)
{
    int n = (blockIdx.x << 2) + (threadIdx.x >> 6);   // grid = NN/4 blocks exactly
    int lane = threadIdx.x & 63;
    int rp0 = __builtin_amdgcn_readfirstlane(row_ptr[n]);
    int rp1 = __builtin_amdgcn_readfirstlane(row_ptr[n + 1]);
    const float4 sd = *(const float4*)&s_all[(size_t)n * 64 + toff + 4];
    float z0 = 0.f, z1 = 0.f, z2 = 0.f, z3 = 0.f;
    float S0 = 0.f, S1 = 0.f, S2 = 0.f, S3 = 0.f;
    for (int e = rp0; e < rp1; ++e) {
        int s = __builtin_amdgcn_readfirstlane(col[e]);
        const float4 ss = *(const float4*)&s_all[(size_t)s * 64 + toff];
        float l0 = ss.x + sd.x, l1 = ss.y + sd.y, l2 = ss.z + sd.z, l3 = ss.w + sd.w;
        l0 = l0 > 0.f ? l0 : 0.2f * l0;
        l1 = l1 > 0.f ? l1 : 0.2f * l1;
        l2 = l2 > 0.f ? l2 : 0.2f * l2;
        l3 = l3 > 0.f ? l3 : 0.2f * l3;
        float p0 = __expf(l0), p1 = __expf(l1), p2 = __expf(l2), p3 = __expf(l3);
        S0 += p0; S1 += p1; S2 += p2; S3 += p3;
        float xv = x[(size_t)s * 64 + lane];
        z0 = fmaf(p0, xv, z0);
        z1 = fmaf(p1, xv, z1);
        z2 = fmaf(p2, xv, z2);
        z3 = fmaf(p3, xv, z3);
    }
    size_t zb = (size_t)n * 256 + lane;
    z[zb]       = z0 / S0;
    z[zb + 64]  = z1 / S1;
    z[zb + 128] = z2 / S2;
    z[zb + 192] = z3 / S3;
}

// ---------------------------------------------------------------------------
// Finalize: out = gelu((acc + bias_sum)/T)
// ---------------------------------------------------------------------------
__global__ void k_finalize(const float* __restrict__ acc,
                           const float* __restrict__ bs, float* __restrict__ out) {
    int i4 = blockIdx.x * 256 + threadIdx.x;
    if (i4 >= NN * 16) return;
    float4 a = ((const float4*)acc)[i4];
    int c = (i4 * 4) & 63;
    float4 b = *(const float4*)&bs[c];
    float4 r;
    r.x = gelu_exact((a.x + b.x) * 0.25f);
    r.y = gelu_exact((a.y + b.y) * 0.25f);
    r.z = gelu_exact((a.z + b.z) * 0.25f);
    r.w = gelu_exact((a.w + b.w) * 0.25f);
    ((float4*)out)[i4] = r;
}

// ---------------------------------------------------------------------------
extern "C" void kernel_launch(void* const* d_in, const int* in_sizes, int n_in,
                              void* d_out, int out_size, void* d_ws, size_t ws_size,
                              hipStream_t stream) {
    const float* fm    = (const float*)d_in[0];
    const float* emb   = (const float*)d_in[1];
    const float* lin_w = (const float*)d_in[2];
    const float* lin_b = (const float*)d_in[3];
    const float* ln_g  = (const float*)d_in[4];
    const float* ln_b  = (const float*)d_in[5];
    const float* Wsrc  = (const float*)d_in[6];
    const float* Wdst  = (const float*)d_in[7];
    const float* asrc  = (const float*)d_in[8];
    const float* adst  = (const float*)d_in[9];
    const float* cbias = (const float*)d_in[10];
    const int*   ei    = (const int*)d_in[11];
    float* out = (float*)d_out;
    (void)in_sizes; (void)n_in; (void)out_size; (void)ws_size;

    char* w = (char*)d_ws;
    size_t off = 0;
    auto alloc = [&](size_t bytes) -> void* {
        void* p = w + off;
        off += (bytes + 255) & ~(size_t)255;
        return p;
    };
    float* wcoll   = (float*)alloc((size_t)LL * 64 * 64 * 4);
    float* bsum    = (float*)alloc((size_t)LL * 64 * 4);
    float* bproj   = (float*)alloc((size_t)LL * TT * 256 * 64 * 4);
    int*   row_ptr = (int*)  alloc((size_t)TT * (NN + 1) * 4);
    int*   cursor  = (int*)  alloc((size_t)TT * NN * 4);
    int*   colarr  = (int*)  alloc((size_t)TT * EPN * 4);
    int*   csum    = (int*)  alloc((size_t)TT * NCH * 4);
    int*   cbase   = (int*)  alloc((size_t)TT * NCH * 4);
    float* x       = (float*)alloc((size_t)NN * 64 * 4);
    float* s_all   = (float*)alloc((size_t)NN * 64 * 4);
    float* acc     = (float*)alloc((size_t)NN * 64 * 4);
    float* z       = (float*)alloc((size_t)NN * 256 * 4);   // also holds raw feature GEMM

    hipMemsetAsync(cursor, 0, (size_t)TT * NN * 4, stream);
    k_prep<<<512, 256, 0, stream>>>(Wsrc, Wdst, asrc, adst, cbias, wcoll, bproj, bsum);
    k_hist<<<(TT * EE + 255) / 256, 256, 0, stream>>>(ei, cursor);
    k_scan1<<<TT * NCH, 256, 0, stream>>>(cursor, csum);
    k_scan2<<<1, 64, 0, stream>>>(csum, cbase, row_ptr);
    k_scan3<<<TT * NCH, 256, 0, stream>>>(cursor, cbase, row_ptr);
    k_scatter<<<(TT * EPN + 255) / 256, 256, 0, stream>>>(ei, cursor, colarr);

    k_gemm64<256, false><<<(NN + 127) / 128, 256, 0, stream>>>(fm, lin_w, z, NN);
    k_feat_post<<<NN / 4, 256, 0, stream>>>(z, lin_b, ln_g, ln_b, emb, x);

    for (int l = 0; l < LL; ++l) {
        k_gemm64<64, false><<<(NN + 127) / 128, 256, 0, stream>>>(
            x, wcoll + l * 4096, s_all, NN);
        hipMemsetAsync(acc, 0, (size_t)NN * 64 * 4, stream);
        for (int t = 0; t < TT; ++t) {
            k_edge<<<NN / 4, 256, 0, stream>>>(
                x, s_all, row_ptr + t * (NN + 1), colarr + (size_t)t * EPN, z, t * 8);
            k_gemm64<256, true><<<(NN + 127) / 128, 256, 0, stream>>>(
                z, bproj + (size_t)(l * TT + t) * 16384, acc, NN);
        }
        k_finalize<<<(NN * 16 + 255) / 256, 256, 0, stream>>>(
            acc, bsum + l * 64, (l == 0) ? x : out);
    }
}

// Round 2
// 1236.051 us; speedup vs baseline: 1.3353x; 1.3353x over previous
//
#include <hip/hip_runtime.h>
#include <hip/hip_bf16.h>
#include <cstdint>

#define NN   100000
#define TT   4
#define EE   250000
#define LL   2
#define NCH  49            // ceil(NN/2048)
#define EPN  (EE + NN)     // 350000

static __device__ __forceinline__ float gelu_exact(float v) {
    return 0.5f * v * (1.0f + erff(v * 0.7071067811865476f));
}
static __device__ __forceinline__ float wave_sum64(float v) {
    #pragma unroll
    for (int m = 32; m; m >>= 1) v += __shfl_xor(v, m, 64);
    return v;
}

// ---------------------------------------------------------------------------
// Prep: collapsed logit weights w_coll[l][d][col] (col = t*8 + side*4 + h),
// permuted/scaled projection Bproj[l][t][h*64+d][c] = 0.25*W_src[l,t,d,h*64+c],
// bias_sum[l][c] = sum_t conv_bias[l,t,c].
// ---------------------------------------------------------------------------
__global__ __launch_bounds__(256) void k_prep(
    const float* __restrict__ Wsrc, const float* __restrict__ Wdst,
    const float* __restrict__ asrc, const float* __restrict__ adst,
    const float* __restrict__ cb,
    float* __restrict__ wcoll, float* __restrict__ bproj, float* __restrict__ bsum)
{
    int id = blockIdx.x * 256 + threadIdx.x;   // grid = 131072 exactly
    {   // Bproj
        int c  = id & 63;
        int hd = (id >> 6) & 255;
        int t  = (id >> 14) & 3;
        int l  = (id >> 16) & 1;
        int h = hd >> 6, d = hd & 63;
        bproj[id] = 0.25f * Wsrc[(((l * 4 + t) * 64 + d) * 256) + h * 64 + c];
    }
    if (id < LL * 64 * 64) {   // w_coll
        int col = id & 63;
        int d   = (id >> 6) & 63;
        int l   = id >> 12;
        int t = col >> 3, side = (col >> 2) & 1, h = col & 3;
        const float* W = side ? Wdst : Wsrc;
        const float* a = side ? adst : asrc;
        int wb = ((l * 4 + t) * 64 + d) * 256 + h * 64;
        int ab = ((l * 4 + t) * 4 + h) * 64;
        float s = 0.f;
        #pragma unroll 8
        for (int c2 = 0; c2 < 64; ++c2) s = fmaf(W[wb + c2], a[ab + c2], s);
        wcoll[id] = s;
    }
    if (id < LL * 64) {        // bias_sum
        int l = id >> 6, c = id & 63;
        float s = 0.f;
        for (int t = 0; t < TT; ++t) s += cb[(l * 4 + t) * 64 + c];
        bsum[id] = s;
    }
}

// ---------------------------------------------------------------------------
// CSR build
// ---------------------------------------------------------------------------
__global__ void k_hist(const int* __restrict__ ei, int* __restrict__ cursor) {
    int id = blockIdx.x * 256 + threadIdx.x;
    if (id >= TT * EE) return;
    int t = id / EE, e = id - t * EE;
    int d = ei[(t * 2 + 1) * EE + e];
    atomicAdd(&cursor[t * NN + d], 1);
}

__global__ __launch_bounds__(256) void k_scan1(const int* __restrict__ deg,
                                               int* __restrict__ csum) {
    int b = blockIdx.x, t = b / NCH, cc = b - t * NCH;
    int tid = threadIdx.x;
    int base = cc * 2048 + tid * 8;
    int s = 0;
    #pragma unroll
    for (int i = 0; i < 8; ++i) {
        int idx = base + i;
        if (idx < NN) s += deg[t * NN + idx] + 1;   // +1: self loop
    }
    #pragma unroll
    for (int m = 32; m; m >>= 1) s += __shfl_xor(s, m, 64);
    __shared__ int ws4[4];
    int lane = tid & 63, wid = tid >> 6;
    if (lane == 0) ws4[wid] = s;
    __syncthreads();
    if (tid == 0) csum[b] = ws4[0] + ws4[1] + ws4[2] + ws4[3];
}

__global__ void k_scan2(const int* __restrict__ csum, int* __restrict__ cbase,
                        int* __restrict__ row_ptr) {
    int t = threadIdx.x;
    if (t >= TT) return;
    int base = 0;
    for (int c = 0; c < NCH; ++c) {
        cbase[t * NCH + c] = base;
        base += csum[t * NCH + c];
    }
    row_ptr[t * (NN + 1) + NN] = base;   // = EE + NN
}

__global__ __launch_bounds__(256) void k_scan3(int* __restrict__ cursor,
                                               const int* __restrict__ cbase,
                                               int* __restrict__ row_ptr) {
    int b = blockIdx.x, t = b / NCH, cc = b - t * NCH;
    int tid = threadIdx.x, lane = tid & 63, wid = tid >> 6;
    int base = cc * 2048 + tid * 8;
    int vals[8], ts = 0;
    #pragma unroll
    for (int i = 0; i < 8; ++i) {
        int idx = base + i;
        int v = (idx < NN) ? cursor[t * NN + idx] + 1 : 0;
        vals[i] = v; ts += v;
    }
    int v = ts;
    #pragma unroll
    for (int off = 1; off < 64; off <<= 1) {
        int u = __shfl_up(v, off, 64);
        if (lane >= off) v += u;
    }
    __shared__ int wt[4];
    if (lane == 63) wt[wid] = v;
    __syncthreads();
    int wbase = 0;
    for (int w = 0; w < wid; ++w) wbase += wt[w];
    int run = cbase[t * NCH + cc] + wbase + (v - ts);
    #pragma unroll
    for (int i = 0; i < 8; ++i) {
        int idx = base + i;
        if (idx < NN) {
            row_ptr[t * (NN + 1) + idx] = run;
            cursor[t * NN + idx] = run;     // becomes scatter write-head
        }
        run += vals[i];
    }
}

__global__ void k_scatter(const int* __restrict__ ei, int* __restrict__ cursor,
                          int* __restrict__ col) {
    int id = blockIdx.x * 256 + threadIdx.x;
    if (id >= TT * EPN) return;
    int t = id / EPN, r = id - t * EPN;
    int s, d;
    if (r < EE) { s = ei[t * 2 * EE + r]; d = ei[(t * 2 + 1) * EE + r]; }
    else        { s = d = r - EE; }
    int pos = atomicAdd(&cursor[t * NN + d], 1);
    col[(size_t)t * EPN + pos] = s;
}

// ---------------------------------------------------------------------------
// Tiled GEMM: C[N,64] = A[N,K] @ B[K,64] with fused epilogue.
// MODE 0: Cout = AB            MODE 1: Cout = Cin + AB
// MODE 2: Cout = gelu((Cin + AB + bias) * 0.25)   (HeteroConv mean + act)
// 128-row tile, K-chunks of 32 in LDS (24.6 KB), 8x4 register tile/thread.
// __launch_bounds__(256,4): VGPR cap 128 -> no spill (round-1 bug: VGPR=256,
// 190 MB scratch-spill writes per dispatch).
// ---------------------------------------------------------------------------
template <int K, int MODE>
__global__ __launch_bounds__(256, 4) void k_gemm64(
    const float* __restrict__ A, const float* __restrict__ B,
    const float* __restrict__ Cin, float* __restrict__ Cout,
    const float* __restrict__ bias, int nrows)
{
    constexpr int KC = 32, RT = 128, LDA = RT + 4;  // LDA=132: b128-aligned, bank-safe
    __shared__ float sA[KC * LDA];   // 16.9 KB
    __shared__ float sB[KC * 64];    // 8 KB
    const int tid = threadIdx.x;
    const int rowbase = blockIdx.x * RT;
    const int jc = tid & 15;            // cols 4*jc..4*jc+3
    const int rg = tid >> 4;            // rows rg*8..rg*8+7

    float acc[8][4];
    #pragma unroll
    for (int i = 0; i < 8; ++i)
        #pragma unroll
        for (int j = 0; j < 4; ++j) acc[i][j] = 0.f;

    for (int kc = 0; kc < K; kc += KC) {
        __syncthreads();
        // stage B chunk: 32x64 = 512 float4, coalesced
        {
            const float4* Bg = (const float4*)(B + kc * 64);
            float4* sB4 = (float4*)sB;
            sB4[tid] = Bg[tid];
            sB4[tid + 256] = Bg[tid + 256];
        }
        // stage A chunk: 128 rows x 32 cols, coalesced (8 x 128B segments per
        // instr), transposed into sA[k][row]
        #pragma unroll
        for (int i = 0; i < 4; ++i) {
            int f = tid + i * 256;      // 0..1023
            int r = f >> 3;             // 0..127
            int cg = f & 7;             // 0..7 (float4 within 32-col chunk)
            int row = rowbase + r;
            float4 v = (row < nrows)
                ? *(const float4*)(A + (size_t)row * K + kc + cg * 4)
                : make_float4(0.f, 0.f, 0.f, 0.f);
            int k0 = cg * 4;
            sA[(k0 + 0) * LDA + r] = v.x;
            sA[(k0 + 1) * LDA + r] = v.y;
            sA[(k0 + 2) * LDA + r] = v.z;
            sA[(k0 + 3) * LDA + r] = v.w;
        }
        __syncthreads();
        #pragma unroll 4
        for (int k = 0; k < KC; ++k) {
            float4 b4 = *(const float4*)&sB[k * 64 + jc * 4];
            float4 a0 = *(const float4*)&sA[k * LDA + rg * 8];
            float4 a1 = *(const float4*)&sA[k * LDA + rg * 8 + 4];
            float av[8] = {a0.x, a0.y, a0.z, a0.w, a1.x, a1.y, a1.z, a1.w};
            float bv[4] = {b4.x, b4.y, b4.z, b4.w};
            #pragma unroll
            for (int i = 0; i < 8; ++i)
                #pragma unroll
                for (int j = 0; j < 4; ++j)
                    acc[i][j] = fmaf(av[i], bv[j], acc[i][j]);
        }
    }
    float4 bv4 = make_float4(0.f, 0.f, 0.f, 0.f);
    if (MODE == 2) bv4 = *(const float4*)(bias + jc * 4);
    #pragma unroll
    for (int i = 0; i < 8; ++i) {
        int row = rowbase + rg * 8 + i;
        if (row < nrows) {
            size_t coff = (size_t)row * 64 + jc * 4;
            float4 r;
            r.x = acc[i][0]; r.y = acc[i][1]; r.z = acc[i][2]; r.w = acc[i][3];
            if (MODE >= 1) {
                float4 c0 = *(const float4*)(Cin + coff);
                r.x += c0.x; r.y += c0.y; r.z += c0.z; r.w += c0.w;
            }
            if (MODE == 2) {
                r.x = gelu_exact((r.x + bv4.x) * 0.25f);
                r.y = gelu_exact((r.y + bv4.y) * 0.25f);
                r.z = gelu_exact((r.z + bv4.z) * 0.25f);
                r.w = gelu_exact((r.w + bv4.w) * 0.25f);
            }
            *(float4*)(Cout + coff) = r;
        }
    }
}

// ---------------------------------------------------------------------------
// Feature epilogue: x = gelu(LN(y + lin_b)) + l2norm(emb).  One wave per row.
// ---------------------------------------------------------------------------
__global__ __launch_bounds__(256) void k_feat_post(
    const float* __restrict__ y, const float* __restrict__ lin_b,
    const float* __restrict__ ln_g, const float* __restrict__ ln_b,
    const float* __restrict__ emb, float* __restrict__ xout)
{
    int n = (blockIdx.x << 2) + (threadIdx.x >> 6);
    int c = threadIdx.x & 63;
    size_t base = (size_t)n * 64 + c;
    float v = y[base] + lin_b[c];
    float mean = wave_sum64(v) * 0.015625f;
    float t = v - mean;
    float var = wave_sum64(t * t) * 0.015625f;
    float vn = t * (1.0f / sqrtf(var + 1e-5f)) * ln_g[c] + ln_b[c];
    float g = gelu_exact(vn);
    float e = emb[base];
    float nrm = sqrtf(wave_sum64(e * e));
    xout[base] = g + e / fmaxf(nrm, 1e-12f);
}

// ---------------------------------------------------------------------------
// Edge aggregation: one wave per destination node.  Single pass over incoming
// edges; z[n][h*64+d] = (sum_e p_e,h * x[src_e,d]) / S[n,h].  No atomics.
// ---------------------------------------------------------------------------
__global__ __launch_bounds__(256) void k_edge(
    const float* __restrict__ x, const float* __restrict__ s_all,
    const int* __restrict__ row_ptr, const int* __restrict__ col,
    float* __restrict__ z, int toff)
{
    int n = (blockIdx.x << 2) + (threadIdx.x >> 6);   // grid = NN/4 blocks exactly
    int lane = threadIdx.x & 63;
    int rp0 = __builtin_amdgcn_readfirstlane(row_ptr[n]);
    int rp1 = __builtin_amdgcn_readfirstlane(row_ptr[n + 1]);
    const float4 sd = *(const float4*)&s_all[(size_t)n * 64 + toff + 4];
    float z0 = 0.f, z1 = 0.f, z2 = 0.f, z3 = 0.f;
    float S0 = 0.f, S1 = 0.f, S2 = 0.f, S3 = 0.f;
    for (int e = rp0; e < rp1; ++e) {
        int s = __builtin_amdgcn_readfirstlane(col[e]);
        const float4 ss = *(const float4*)&s_all[(size_t)s * 64 + toff];
        float l0 = ss.x + sd.x, l1 = ss.y + sd.y, l2 = ss.z + sd.z, l3 = ss.w + sd.w;
        l0 = l0 > 0.f ? l0 : 0.2f * l0;
        l1 = l1 > 0.f ? l1 : 0.2f * l1;
        l2 = l2 > 0.f ? l2 : 0.2f * l2;
        l3 = l3 > 0.f ? l3 : 0.2f * l3;
        float p0 = __expf(l0), p1 = __expf(l1), p2 = __expf(l2), p3 = __expf(l3);
        S0 += p0; S1 += p1; S2 += p2; S3 += p3;
        float xv = x[(size_t)s * 64 + lane];
        z0 = fmaf(p0, xv, z0);
        z1 = fmaf(p1, xv, z1);
        z2 = fmaf(p2, xv, z2);
        z3 = fmaf(p3, xv, z3);
    }
    size_t zb = (size_t)n * 256 + lane;
    z[zb]       = z0 / S0;
    z[zb + 64]  = z1 / S1;
    z[zb + 128] = z2 / S2;
    z[zb + 192] = z3 / S3;
}

// ---------------------------------------------------------------------------
extern "C" void kernel_launch(void* const* d_in, const int* in_sizes, int n_in,
                              void* d_out, int out_size, void* d_ws, size_t ws_size,
                              hipStream_t stream) {
    const float* fm    = (const float*)d_in[0];
    const float* emb   = (const float*)d_in[1];
    const float* lin_w = (const float*)d_in[2];
    const float* lin_b = (const float*)d_in[3];
    const float* ln_g  = (const float*)d_in[4];
    const float* ln_b  = (const float*)d_in[5];
    const float* Wsrc  = (const float*)d_in[6];
    const float* Wdst  = (const float*)d_in[7];
    const float* asrc  = (const float*)d_in[8];
    const float* adst  = (const float*)d_in[9];
    const float* cbias = (const float*)d_in[10];
    const int*   ei    = (const int*)d_in[11];
    float* out = (float*)d_out;
    (void)in_sizes; (void)n_in; (void)out_size; (void)ws_size;

    char* w = (char*)d_ws;
    size_t off = 0;
    auto alloc = [&](size_t bytes) -> void* {
        void* p = w + off;
        off += (bytes + 255) & ~(size_t)255;
        return p;
    };
    float* wcoll   = (float*)alloc((size_t)LL * 64 * 64 * 4);
    float* bsum    = (float*)alloc((size_t)LL * 64 * 4);
    float* bproj   = (float*)alloc((size_t)LL * TT * 256 * 64 * 4);
    int*   row_ptr = (int*)  alloc((size_t)TT * (NN + 1) * 4);
    int*   cursor  = (int*)  alloc((size_t)TT * NN * 4);
    int*   colarr  = (int*)  alloc((size_t)TT * EPN * 4);
    int*   csum    = (int*)  alloc((size_t)TT * NCH * 4);
    int*   cbase   = (int*)  alloc((size_t)TT * NCH * 4);
    float* x       = (float*)alloc((size_t)NN * 64 * 4);
    float* s_all   = (float*)alloc((size_t)NN * 64 * 4);
    float* acc     = (float*)alloc((size_t)NN * 64 * 4);
    float* z       = (float*)alloc((size_t)NN * 256 * 4);   // also holds raw feature GEMM

    hipMemsetAsync(cursor, 0, (size_t)TT * NN * 4, stream);
    k_prep<<<512, 256, 0, stream>>>(Wsrc, Wdst, asrc, adst, cbias, wcoll, bproj, bsum);
    k_hist<<<(TT * EE + 255) / 256, 256, 0, stream>>>(ei, cursor);
    k_scan1<<<TT * NCH, 256, 0, stream>>>(cursor, csum);
    k_scan2<<<1, 64, 0, stream>>>(csum, cbase, row_ptr);
    k_scan3<<<TT * NCH, 256, 0, stream>>>(cursor, cbase, row_ptr);
    k_scatter<<<(TT * EPN + 255) / 256, 256, 0, stream>>>(ei, cursor, colarr);

    const int GB = (NN + 127) / 128;
    k_gemm64<256, 0><<<GB, 256, 0, stream>>>(fm, lin_w, nullptr, z, nullptr, NN);
    k_feat_post<<<NN / 4, 256, 0, stream>>>(z, lin_b, ln_g, ln_b, emb, x);

    for (int l = 0; l < LL; ++l) {
        k_gemm64<64, 0><<<GB, 256, 0, stream>>>(
            x, wcoll + l * 4096, nullptr, s_all, nullptr, NN);
        for (int t = 0; t < TT; ++t) {
            k_edge<<<NN / 4, 256, 0, stream>>>(
                x, s_all, row_ptr + t * (NN + 1), colarr + (size_t)t * EPN, z, t * 8);
            const float* bp = bproj + (size_t)(l * TT + t) * 16384;
            if (t == 0)
                k_gemm64<256, 0><<<GB, 256, 0, stream>>>(z, bp, nullptr, acc, nullptr, NN);
            else if (t < TT - 1)
                k_gemm64<256, 1><<<GB, 256, 0, stream>>>(z, bp, acc, acc, nullptr, NN);
            else
                k_gemm64<256, 2><<<GB, 256, 0, stream>>>(
                    z, bp, acc, (l == 0) ? x : out, bsum + l * 64, NN);
        }
    }
}